// Round 11
// baseline (420.527 us; speedup 1.0000x reference)
//
#include <hip/hip_runtime.h>
#include <math.h>

#define BATCH 16
#define GRID  80
#define NANCH 3
#define KTOP  300
#define NBOX  (NANCH*GRID*GRID)   // 19200
#define SORT_CAP 8192

__device__ __forceinline__ float sigmoidf_(float x){ return 1.0f/(1.0f+expf(-x)); }

// ---------------- 3x3 stride-2 conv + SiLU, v7 (round-0 exact; used for conv1) ----------------
template<int CIN,int COUT,int C,int ICCH,int HIN,int HOUT,int TX,int TY,int MINW>
__global__ __launch_bounds__(256, MINW) void conv3x3s2_v7(
    const float* __restrict__ in, const float* __restrict__ w,
    const float* __restrict__ bias, float* __restrict__ out)
{
  constexpr int NTX = TX/4, NTY = TY/2, NSP = NTX*NTY, OCG = COUT/C;
  static_assert(NSP*OCG == 256, "bad thread layout");
  static_assert(C==4 || C==8, "C must be 4 or 8");
  constexpr int HR = 2*TY+1, HC = 2*TX+1;
  constexpr int NB4  = HC/4;
  constexpr int PADC = ((HC+3)/4)*4 + 4;
  constexpr int ILDSC = HR*PADC;
  constexpr int TBX = HOUT/TX, TBY = HOUT/TY;
  static_assert(TBX*TX == HOUT && TBY*TY == HOUT, "no masking");
  constexpr int NCH  = CIN/ICCH;
  constexpr int NH4  = ICCH*HR*NB4;
  constexpr int NH1  = ICCH*HR;
  constexpr int NWT  = ICCH*9*COUT;
  constexpr int NLD4 = (NH4+255)/256;
  constexpr int NLD1 = (NH1+255)/256;
  constexpr int NLDW = (NWT+255)/256;
  __shared__ float ilds[2][ICCH*ILDSC];
  __shared__ float wlds[2][NWT];

  const int t  = threadIdx.x;
  const int sx = t % NTX;
  const int sy = (t / NTX) % NTY;
  const int og = t / NSP;
  int blk = blockIdx.x;
  const int bx = blk % TBX; blk /= TBX;
  const int by = blk % TBY; blk /= TBY;
  const int b  = blk;

  const int ix0 = bx*2*TX, iy0 = by*2*TY;
  const int ylim = (iy0 + HR <= HIN) ? HR : (HIN - iy0);
  const bool tail_ok = (ix0 + NB4*4 < HIN);

  float4 hreg[NLD4];
  float  treg[NLD1];
  float  wreg[NLDW];

  auto load_regs = [&](int c0){
    #pragma unroll
    for (int l=0;l<NLD4;++l){
      int i = t + 256*l;
      float4 v = make_float4(0.f,0.f,0.f,0.f);
      if (i < NH4){
        int c = i/(HR*NB4), rm = i - c*(HR*NB4);
        int r = rm/NB4, m = rm - r*NB4;
        if (r < ylim)
          v = *(const float4*)(in + (size_t)(b*CIN + c0 + c)*HIN*HIN
                                  + (size_t)(iy0+r)*HIN + ix0 + 4*m);
      }
      hreg[l] = v;
    }
    #pragma unroll
    for (int l=0;l<NLD1;++l){
      int i = t + 256*l;
      float v = 0.f;
      if (i < NH1){
        int c = i/HR, r = i - c*HR;
        if (r < ylim && tail_ok)
          v = in[(size_t)(b*CIN + c0 + c)*HIN*HIN + (size_t)(iy0+r)*HIN + ix0 + NB4*4];
      }
      treg[l] = v;
    }
    #pragma unroll
    for (int l=0;l<NLDW;++l){
      int i = t + 256*l;
      float v = 0.f;
      if (i < NWT){
        int oc  = i % COUT;
        int k   = (i / COUT) % 9;
        int icl = i / (9*COUT);
        v = w[((size_t)oc*CIN + c0+icl)*9 + k];
      }
      wreg[l] = v;
    }
  };

  auto write_lds = [&](int bufi){
    #pragma unroll
    for (int l=0;l<NLD4;++l){
      int i = t + 256*l;
      if (i < NH4){
        int c = i/(HR*NB4), rm = i - c*(HR*NB4);
        int r = rm/NB4, m = rm - r*NB4;
        *(float4*)(&ilds[bufi][c*ILDSC + r*PADC + 4*((r>>2)&1) + 4*m]) = hreg[l];
      }
    }
    #pragma unroll
    for (int l=0;l<NLD1;++l){
      int i = t + 256*l;
      if (i < NH1){
        int c = i/HR, r = i - c*HR;
        ilds[bufi][c*ILDSC + r*PADC + 4*((r>>2)&1) + NB4*4] = treg[l];
      }
    }
    #pragma unroll
    for (int l=0;l<NLDW;++l){
      int i = t + 256*l;
      if (i < NWT) wlds[bufi][i] = wreg[l];
    }
  };

  float acc[C][2][4];
  #pragma unroll
  for (int j=0;j<C;++j){
    float bv = bias[og*C+j];
    #pragma unroll
    for (int py=0;py<2;++py)
      #pragma unroll
      for (int px=0;px<4;++px) acc[j][py][px]=bv;
  }

  load_regs(0);
  write_lds(0);
  __syncthreads();

  #pragma unroll 1
  for (int ch=0; ch<NCH; ++ch){
    const int cur = ch & 1;
    if (ch+1 < NCH) load_regs((ch+1)*ICCH);

    #pragma unroll 1
    for (int icl=0; icl<ICCH; ++icl){
      const float* wpb = &wlds[cur][icl*9*COUT] + og*C;
      float4 wk0[9], wk1[9];
      #pragma unroll
      for (int k=0;k<9;++k){
        wk0[k] = *(const float4*)(wpb + k*COUT);
        if constexpr (C==8) wk1[k] = *(const float4*)(wpb + k*COUT + 4);
      }
      const float* ipb = &ilds[cur][icl*ILDSC] + 8*sx;
      float rw[5][12];
      #pragma unroll
      for (int r=0;r<5;++r){
        const int rr = 4*sy + r;
        const float* rp = ipb + rr*PADC + 4*((rr>>2)&1);
        #pragma unroll
        for (int m=0;m<3;++m){
          float4 v4 = *(const float4*)(rp + 4*m);
          rw[r][4*m+0]=v4.x; rw[r][4*m+1]=v4.y; rw[r][4*m+2]=v4.z; rw[r][4*m+3]=v4.w;
        }
      }
      #pragma unroll
      for (int py=0;py<2;++py)
        #pragma unroll
        for (int ky=0;ky<3;++ky)
          #pragma unroll
          for (int kx=0;kx<3;++kx){
            const float4 wa = wk0[ky*3+kx];
            #pragma unroll
            for (int px=0;px<4;++px){
              const float xv = rw[2*py+ky][2*px+kx];
              acc[0][py][px] += xv*wa.x; acc[1][py][px] += xv*wa.y;
              acc[2][py][px] += xv*wa.z; acc[3][py][px] += xv*wa.w;
            }
            if constexpr (C==8){
              const float4 wb = wk1[ky*3+kx];
              #pragma unroll
              for (int px=0;px<4;++px){
                const float xv = rw[2*py+ky][2*px+kx];
                acc[4][py][px] += xv*wb.x; acc[5][py][px] += xv*wb.y;
                acc[6][py][px] += xv*wb.z; acc[7][py][px] += xv*wb.w;
              }
            }
          }
    }

    if (ch+1 < NCH) write_lds((ch+1)&1);
    __syncthreads();
  }

  const int oxb = bx*TX + sx*4;
  #pragma unroll
  for (int j=0;j<C;++j){
    int oc = og*C+j;
    #pragma unroll
    for (int py=0;py<2;++py){
      int oy = by*TY + sy*2 + py;
      float4 o4;
      float z0=acc[j][py][0], z1=acc[j][py][1], z2=acc[j][py][2], z3=acc[j][py][3];
      o4.x = z0/(1.0f+expf(-z0));
      o4.y = z1/(1.0f+expf(-z1));
      o4.z = z2/(1.0f+expf(-z2));
      o4.w = z3/(1.0f+expf(-z3));
      *(float4*)(out + ((size_t)(b*COUT+oc)*HOUT + oy)*HOUT + oxb) = o4;
    }
  }
}

// ---------------- conv2 v12: weights via wave-uniform scalar loads (SGPR), no wlds ----------
// (proven round 7; W2=18KB fits scalar L1 -> s_loads are cache hits. Round-10 lesson:
// this trick does NOT extend to W3=73KB, which thrashes the scalar cache.)
__global__ __launch_bounds__(256, 1) void conv2_v12(
    const float* __restrict__ in, const float* __restrict__ w,
    const float* __restrict__ bias, float* __restrict__ out)
{
  constexpr int CIN=16, COUT=32, HIN=320, HOUT=160, TX=32, TY=16;
  constexpr int NTX=8, NTY=8;
  constexpr int C=8;
  constexpr int HR=2*TY+1;              // 33
  constexpr int NB4=(2*TX+1)/4;         // 16
  constexpr int PADC=72;
  constexpr int ILDSC=HR*PADC;          // 2376
  constexpr int TBX=HOUT/TX, TBY=HOUT/TY;  // 5, 10
  constexpr int NH4=HR*NB4;             // 528
  constexpr int NH1=HR;                 // 33
  constexpr int NLD4=(NH4+255)/256;     // 3
  __shared__ float ilds[2][ILDSC];      // 19008 B total

  const int t  = threadIdx.x;
  const int sx = t % NTX;
  const int sy = (t / NTX) % NTY;
  const int og = t / 64;                            // == wave id -> wave-uniform
  const int ocb = __builtin_amdgcn_readfirstlane(og * C);  // scalar oc base

  int blk = blockIdx.x;
  const int bx = blk % TBX; blk /= TBX;
  const int by = blk % TBY; blk /= TBY;
  const int b  = blk;

  const int ix0 = bx*2*TX, iy0 = by*2*TY;
  const int ylim = (iy0 + HR <= HIN) ? HR : (HIN - iy0);
  const bool tail_ok = (ix0 + NB4*4 < HIN);

  float4 hreg[NLD4];
  float  treg;

  auto load_regs = [&](int c0){
    #pragma unroll
    for (int l=0;l<NLD4;++l){
      int i = t + 256*l;
      float4 v = make_float4(0.f,0.f,0.f,0.f);
      if (i < NH4){
        int r = i/NB4, m = i - r*NB4;
        if (r < ylim)
          v = *(const float4*)(in + (size_t)(b*CIN + c0)*HIN*HIN
                                  + (size_t)(iy0+r)*HIN + ix0 + 4*m);
      }
      hreg[l] = v;
    }
    {
      float v = 0.f;
      if (t < NH1){
        int r = t;
        if (r < ylim && tail_ok)
          v = in[(size_t)(b*CIN + c0)*HIN*HIN + (size_t)(iy0+r)*HIN + ix0 + NB4*4];
      }
      treg = v;
    }
  };

  auto write_lds = [&](int bufi){
    #pragma unroll
    for (int l=0;l<NLD4;++l){
      int i = t + 256*l;
      if (i < NH4){
        int r = i/NB4, m = i - r*NB4;
        *(float4*)(&ilds[bufi][r*PADC + 4*((r>>2)&1) + 4*m]) = hreg[l];
      }
    }
    if (t < NH1){
      int r = t;
      ilds[bufi][r*PADC + 4*((r>>2)&1) + NB4*4] = treg;
    }
  };

  float acc[C][2][4];
  #pragma unroll
  for (int j=0;j<C;++j){
    float bv = bias[og*C+j];
    #pragma unroll
    for (int py=0;py<2;++py)
      #pragma unroll
      for (int px=0;px<4;++px) acc[j][py][px]=bv;
  }

  load_regs(0);
  write_lds(0);
  __syncthreads();

  #pragma unroll 1
  for (int ch=0; ch<CIN; ++ch){
    const int cur = ch & 1;
    if (ch+1 < CIN) load_regs(ch+1);

    // wave-uniform weight base for this input channel: w[(ocb+j)*CIN + ch][ky][kx]
    const float* wg = w + ((size_t)ocb*CIN + ch)*9;
    const float* ipb = &ilds[cur][0] + 8*sx;

    #pragma unroll
    for (int ky=0;ky<3;++ky){
      // 24 wave-uniform weight scalars for this (ch, ky) -> SGPRs via s_load
      float wv[3][8];
      #pragma unroll
      for (int j=0;j<8;++j){
        #pragma unroll
        for (int kx=0;kx<3;++kx)
          wv[kx][j] = wg[(size_t)j*(CIN*9) + ky*3 + kx];
      }
      // ---- py=0 half: row 4sy+ky (12 live row regs)
      {
        float ra[12];
        const int rr0 = 4*sy + ky;
        const float* rp0 = ipb + rr0*PADC + 4*((rr0>>2)&1);
        #pragma unroll
        for (int m=0;m<3;++m){
          float4 v0 = *(const float4*)(rp0 + 4*m);
          ra[4*m+0]=v0.x; ra[4*m+1]=v0.y; ra[4*m+2]=v0.z; ra[4*m+3]=v0.w;
        }
        #pragma unroll
        for (int kx=0;kx<3;++kx){
          #pragma unroll
          for (int px=0;px<4;++px){
            const float xv = ra[2*px+kx];
            acc[0][0][px] += xv*wv[kx][0]; acc[1][0][px] += xv*wv[kx][1];
            acc[2][0][px] += xv*wv[kx][2]; acc[3][0][px] += xv*wv[kx][3];
            acc[4][0][px] += xv*wv[kx][4]; acc[5][0][px] += xv*wv[kx][5];
            acc[6][0][px] += xv*wv[kx][6]; acc[7][0][px] += xv*wv[kx][7];
          }
        }
      }
      // ---- py=1 half: row 4sy+ky+2
      {
        float rb[12];
        const int rr1 = 4*sy + ky + 2;
        const float* rp1 = ipb + rr1*PADC + 4*((rr1>>2)&1);
        #pragma unroll
        for (int m=0;m<3;++m){
          float4 v1 = *(const float4*)(rp1 + 4*m);
          rb[4*m+0]=v1.x; rb[4*m+1]=v1.y; rb[4*m+2]=v1.z; rb[4*m+3]=v1.w;
        }
        #pragma unroll
        for (int kx=0;kx<3;++kx){
          #pragma unroll
          for (int px=0;px<4;++px){
            const float xv = rb[2*px+kx];
            acc[0][1][px] += xv*wv[kx][0]; acc[1][1][px] += xv*wv[kx][1];
            acc[2][1][px] += xv*wv[kx][2]; acc[3][1][px] += xv*wv[kx][3];
            acc[4][1][px] += xv*wv[kx][4]; acc[5][1][px] += xv*wv[kx][5];
            acc[6][1][px] += xv*wv[kx][6]; acc[7][1][px] += xv*wv[kx][7];
          }
        }
      }
    }

    if (ch+1 < CIN) write_lds((ch+1)&1);
    __syncthreads();
  }

  const int oxb = bx*TX + sx*4;
  #pragma unroll
  for (int j=0;j<C;++j){
    int oc = og*C+j;
    #pragma unroll
    for (int py=0;py<2;++py){
      int oy = by*TY + sy*2 + py;
      float4 o4;
      float z0=acc[j][py][0], z1=acc[j][py][1], z2=acc[j][py][2], z3=acc[j][py][3];
      o4.x = z0/(1.0f+expf(-z0));
      o4.y = z1/(1.0f+expf(-z1));
      o4.z = z2/(1.0f+expf(-z2));
      o4.w = z3/(1.0f+expf(-z3));
      *(float4*)(out + ((size_t)(b*COUT+oc)*HOUT + oy)*HOUT + oxb) = o4;
    }
  }
}

// ---------------- conv3 + head + decode, fused v5 ----------------
// Round-10: v4's s_load weights thrash scalar L1 (W3=73KB >> 16KB) -> regressed.
// LDS-pipe model: v2/v3 issue ~24-27 ds_read_b128 per icl per wave -> ~69us of LDS
// pipe per CU = the kernel. v5 improves reads/FMA with C=8 + py=2 (15 data + 18 wt
// reads per 576 FMAs, vs v2's 24/288) at 128 threads/block: LDS 40KB -> 4 blocks/CU
// = 2 waves/EU -> allocator VGPR budget 256 >= natural ~200, no spill (law-safe).
// Per-acc-element FMA order (ic, ky, kx) ascending -> bit-exact. f3l stride-69
// epilogue + global-Wh head unchanged (loop stride 128; ua still wave-uniform).
// Canaries: WRITE ~6MB (spill), FETCH ~49MB.
__global__ __launch_bounds__(128, 1) void conv3_decode_fused(
    const float* __restrict__ in,   // f2
    const float* __restrict__ w,    // W3
    const float* __restrict__ bias, // b3
    const float* __restrict__ wh,   // Wh [48][64]
    const float* __restrict__ bh,   // bh [48]
    float* __restrict__ boxes, float* __restrict__ scores)
{
  constexpr int CIN=32, COUT=64, C=8, ICCH=4, HIN=160, TX=16, TY=8;
  constexpr int NTX=4, NTY=4;                         // 16 spatial x 8 ocg = 128 thr
  constexpr int HR=2*TY+1, HC=2*TX+1;                 // 17,33
  constexpr int NB4=HC/4;                             // 8
  constexpr int PADC=((HC+3)/4)*4+4;                  // 40
  constexpr int ILDSC=HR*PADC;                        // 680
  constexpr int TBX=5, TBY=10;
  constexpr int NCH=CIN/ICCH;                         // 8
  constexpr int NH4=ICCH*HR*NB4;                      // 544
  constexpr int NH1=ICCH*HR;                          // 68
  constexpr int NWT=ICCH*9*COUT;                      // 2304
  constexpr int NT=128;
  constexpr int NLD4=(NH4+NT-1)/NT;                   // 5
  constexpr int NLD1=(NH1+NT-1)/NT;                   // 1
  constexpr int NLDW=(NWT+NT-1)/NT;                   // 18
  constexpr int F3S=69;                               // f3l row stride (mod 32 = 5)
  __shared__ float smem[10048];
  float* ildsb = smem;              // [2][ICCH*ILDSC] = 5440
  float* wldsb = smem + 5440;       // [2][NWT] = 4608 (ends 10048)
  float* f3l   = smem;              // [128][69] = 8832 aliased (post-conv)

  const int t  = threadIdx.x;
  const int sx = t % NTX;           // 4 cols of 4 px
  const int sy = (t / NTX) % NTY;   // 4 row-pairs
  const int og = t / 16;            // 8 oc-groups of 8
  int blk = blockIdx.x;
  const int bx = blk % TBX; blk /= TBX;
  const int by = blk % TBY; blk /= TBY;
  const int b  = blk;

  const int ix0 = bx*2*TX, iy0 = by*2*TY;
  const int ylim = (iy0 + HR <= HIN) ? HR : (HIN - iy0);
  const bool tail_ok = (ix0 + NB4*4 < HIN);

  float4 hreg[NLD4];
  float  treg[NLD1];
  float  wreg[NLDW];

  auto load_regs = [&](int c0){
    #pragma unroll
    for (int l=0;l<NLD4;++l){
      int i = t + NT*l;
      float4 v = make_float4(0.f,0.f,0.f,0.f);
      if (i < NH4){
        int c = i/(HR*NB4), rm = i - c*(HR*NB4);
        int r = rm/NB4, m = rm - r*NB4;
        if (r < ylim)
          v = *(const float4*)(in + (size_t)(b*CIN + c0 + c)*HIN*HIN
                                  + (size_t)(iy0+r)*HIN + ix0 + 4*m);
      }
      hreg[l] = v;
    }
    #pragma unroll
    for (int l=0;l<NLD1;++l){
      int i = t + NT*l;
      float v = 0.f;
      if (i < NH1){
        int c = i/HR, r = i - c*HR;
        if (r < ylim && tail_ok)
          v = in[(size_t)(b*CIN + c0 + c)*HIN*HIN + (size_t)(iy0+r)*HIN + ix0 + NB4*4];
      }
      treg[l] = v;
    }
    #pragma unroll
    for (int l=0;l<NLDW;++l){
      int i = t + NT*l;
      float v = 0.f;
      if (i < NWT){
        int oc  = i % COUT;
        int k   = (i / COUT) % 9;
        int icl = i / (9*COUT);
        v = w[((size_t)oc*CIN + c0+icl)*9 + k];
      }
      wreg[l] = v;
    }
  };

  auto write_lds = [&](int bufi){
    #pragma unroll
    for (int l=0;l<NLD4;++l){
      int i = t + NT*l;
      if (i < NH4){
        int c = i/(HR*NB4), rm = i - c*(HR*NB4);
        int r = rm/NB4, m = rm - r*NB4;
        *(float4*)(&ildsb[bufi*(ICCH*ILDSC) + c*ILDSC + r*PADC + 4*((r>>2)&1) + 4*m]) = hreg[l];
      }
    }
    #pragma unroll
    for (int l=0;l<NLD1;++l){
      int i = t + NT*l;
      if (i < NH1){
        int c = i/HR, r = i - c*HR;
        ildsb[bufi*(ICCH*ILDSC) + c*ILDSC + r*PADC + 4*((r>>2)&1) + NB4*4] = treg[l];
      }
    }
    #pragma unroll
    for (int l=0;l<NLDW;++l){
      int i = t + NT*l;
      if (i < NWT) wldsb[bufi*NWT + i] = wreg[l];
    }
  };

  float acc[C][2][4];
  #pragma unroll
  for (int j=0;j<C;++j){
    float bv = bias[og*C+j];
    #pragma unroll
    for (int py=0;py<2;++py)
      #pragma unroll
      for (int px=0;px<4;++px) acc[j][py][px]=bv;
  }

  load_regs(0);
  write_lds(0);
  __syncthreads();

  #pragma unroll 1
  for (int ch=0; ch<NCH; ++ch){
    const int cur = ch & 1;
    if (ch+1 < NCH) load_regs((ch+1)*ICCH);

    #pragma unroll 1
    for (int icl=0; icl<ICCH; ++icl){
      const float* wpb = &wldsb[cur*NWT + icl*9*COUT] + og*C;
      const float* ipb = &ildsb[cur*(ICCH*ILDSC) + icl*ILDSC] + 8*sx;
      float rw[5][12];
      #pragma unroll
      for (int r=0;r<5;++r){
        const int rr = 4*sy + r;
        const float* rp = ipb + rr*PADC + 4*((rr>>2)&1);
        #pragma unroll
        for (int m=0;m<3;++m){
          float4 v4 = *(const float4*)(rp + 4*m);
          rw[r][4*m+0]=v4.x; rw[r][4*m+1]=v4.y; rw[r][4*m+2]=v4.z; rw[r][4*m+3]=v4.w;
        }
      }
      #pragma unroll
      for (int py=0;py<2;++py)
        #pragma unroll
        for (int ky=0;ky<3;++ky)
          #pragma unroll
          for (int kx=0;kx<3;++kx){
            const float4 wa = *(const float4*)(wpb + (ky*3+kx)*COUT);
            const float4 wb = *(const float4*)(wpb + (ky*3+kx)*COUT + 4);
            #pragma unroll
            for (int px=0;px<4;++px){
              const float xv = rw[2*py+ky][2*px+kx];
              acc[0][py][px] += xv*wa.x; acc[1][py][px] += xv*wa.y;
              acc[2][py][px] += xv*wa.z; acc[3][py][px] += xv*wa.w;
              acc[4][py][px] += xv*wb.x; acc[5][py][px] += xv*wb.y;
              acc[6][py][px] += xv*wb.z; acc[7][py][px] += xv*wb.w;
            }
          }
    }

    if (ch+1 < NCH) write_lds((ch+1)&1);
    __syncthreads();
  }

  // ---- epilogue: SiLU -> LDS f3 tile (stride 69, conflict-light)
  #pragma unroll
  for (int j=0;j<C;++j){
    int oc = og*C+j;
    #pragma unroll
    for (int py=0;py<2;++py)
      #pragma unroll
      for (int px=0;px<4;++px){
        int pxidx = (sy*2+py)*16 + sx*4+px;
        float z = acc[j][py][px];
        f3l[pxidx*F3S + oc] = z/(1.0f+expf(-z));
      }
  }
  __syncthreads();

  // ---- head (6 channels) + sigmoid + decode + write; Wh/bh direct from global
  // ua = q>>7 is wave-uniform: iter k has q = t + 128k, so ua = k per 128-thread pass.
  const float awv[3] = {4.0f, 8.0f, 13.0f};
  const float ahv[3] = {5.0f, 10.0f, 16.0f};
  const int chs[6] = {0,1,2,3,4,15};
  for (int q=t; q<384; q+=NT){
    int p = q & 127;
    const int ua = __builtin_amdgcn_readfirstlane(q >> 7);
    float ac[6];
    #pragma unroll
    for (int j=0;j<6;++j) ac[j] = bh[ua*16 + chs[j]];
    const float* fp = f3l + p*F3S;
    const float* wp = wh + (size_t)ua*16*64;
    #pragma unroll 4
    for (int ic=0; ic<64; ic+=4){
      float4 fv = *(const float4*)(fp + ic);
      #pragma unroll
      for (int j=0;j<6;++j){
        float4 wv = *(const float4*)(wp + chs[j]*64 + ic);
        ac[j] += fv.x*wv.x; ac[j] += fv.y*wv.y;
        ac[j] += fv.z*wv.z; ac[j] += fv.w*wv.w;
      }
    }
    float p0 = sigmoidf_(ac[0]);
    float p1 = sigmoidf_(ac[1]);
    float p2 = sigmoidf_(ac[2]);
    float p3 = sigmoidf_(ac[3]);
    float p4 = sigmoidf_(ac[4]);
    float p15= sigmoidf_(ac[5]);
    int gx = bx*16 + (p & 15), gy = by*8 + (p >> 4);
    float cx = (p0*2.0f - 0.5f + (float)gx)*8.0f;
    float cy = (p1*2.0f - 0.5f + (float)gy)*8.0f;
    float ww = p2*2.0f; ww = ww*ww*awv[ua];
    float hh = p3*2.0f; hh = hh*hh*ahv[ua];
    float sc = p4*p15;
    sc = (sc > 0.5f) ? sc : 0.0f;
    int bi = ua*GRID*GRID + gy*GRID + gx;
    float* bo = boxes + ((size_t)b*NBOX + bi)*4;
    bo[0] = cx - ww*0.5f;
    bo[1] = cy - hh*0.5f;
    bo[2] = cx + ww*0.5f;
    bo[3] = cy + hh*0.5f;
    scores[(size_t)b*NBOX + bi] = sc;
  }
}

// ---------------- kernel A: compact + bitonic-sort top-K + gather ----------------
__global__ __launch_bounds__(1024) void topk_kernel(
    const float* __restrict__ boxes, const float* __restrict__ scores,
    float* __restrict__ nmsbuf, int* __restrict__ mcnt)
{
  __shared__ unsigned long long keys[SORT_CAP];  // 64 KB
  __shared__ int   cntM;
  __shared__ int   sel[KTOP];
  __shared__ float selsc[KTOP];
  __shared__ int   wsum[16];
  __shared__ float rs[16];
  __shared__ int   ri[16];
  __shared__ unsigned clm[(NBOX+31)/32];

  const int b = blockIdx.x;
  const int t = threadIdx.x;
  const int lane = t & 63, wv = t >> 6;
  const float* scp = scores + (size_t)b*NBOX;

  if (t == 0) cntM = 0;
  __syncthreads();

  for (int i=t; i<NBOX; i+=1024){
    float v = scp[i];
    if (v > 0.0f){
      int p = atomicAdd(&cntM, 1);
      if (p < SORT_CAP)
        keys[p] = ((unsigned long long)__float_as_uint(v) << 32)
                | (unsigned)(0xFFFFFFFFu - (unsigned)i);
    }
  }
  __syncthreads();
  const int M = cntM;
  if (t == 0) mcnt[b] = M;

  if (M <= SORT_CAP){
    int P = 64; while (P < M) P <<= 1;
    for (int i=t; i<P; i+=1024) if (i >= M) keys[i] = 0ULL;
    __syncthreads();
    for (int k=2; k<=P; k<<=1){
      for (int j=k>>1; j>0; j>>=1){
        for (int i=t; i<P; i+=1024){
          int ixj = i ^ j;
          if (ixj > i){
            unsigned long long a = keys[i], c = keys[ixj];
            bool up = ((i & k) == 0);
            if (up ? (a < c) : (a > c)){ keys[i] = c; keys[ixj] = a; }
          }
        }
        __syncthreads();
      }
    }
    const int top = (M < KTOP) ? M : KTOP;
    if (t < top){
      unsigned long long kk = keys[t];
      selsc[t] = __uint_as_float((unsigned)(kk >> 32));
      sel[t]   = (int)(0xFFFFFFFFu - (unsigned)(kk & 0xFFFFFFFFu));
    }
    if (M < KTOP){
      const int need = KTOP - M;
      const int Cc = (NBOX + 1023)/1024;
      int lo = t*Cc, hi = lo+Cc; if (hi > NBOX) hi = NBOX; if (lo > NBOX) lo = NBOX;
      int zc = 0;
      for (int i=lo;i<hi;i++) if (scp[i] <= 0.0f) zc++;
      int v = zc;
      #pragma unroll
      for (int off=1; off<64; off<<=1){
        int n = __shfl_up(v, off);
        if (lane >= off) v += n;
      }
      if (lane == 63) wsum[wv] = v;
      __syncthreads();
      if (t == 0){
        int a = 0;
        for (int w=0; w<16; w++){ int tmp = wsum[w]; wsum[w] = a; a += tmp; }
      }
      __syncthreads();
      int r = wsum[wv] + v - zc;
      for (int i=lo;i<hi;i++){
        if (scp[i] <= 0.0f){
          if (r < need){ sel[M+r] = i; selsc[M+r] = 0.0f; }
          r++;
        }
      }
    }
    __syncthreads();
  } else {
    for (int i=t; i<(NBOX+31)/32; i+=1024) clm[i] = 0u;
    __syncthreads();
    for (int k=0;k<KTOP;k++){
      float best = -2.0f; int bi = NBOX;
      for (int i=t;i<NBOX;i+=1024){
        if (!((clm[i>>5] >> (i&31)) & 1u)){
          float v = scp[i];
          if (v > best){ best=v; bi=i; }
        }
      }
      #pragma unroll
      for (int off=32; off>0; off>>=1){
        float ov = __shfl_down(best, off);
        int   oi = __shfl_down(bi,   off);
        if (ov > best || (ov == best && oi < bi)){ best=ov; bi=oi; }
      }
      if (lane == 0){ rs[wv]=best; ri[wv]=bi; }
      __syncthreads();
      if (t == 0){
        for (int w=1; w<16; w++)
          if (rs[w] > best || (rs[w] == best && ri[w] < bi)){ best=rs[w]; bi=ri[w]; }
        sel[k]=bi; selsc[k]=best; clm[bi>>5] |= (1u << (bi&31));
      }
      __syncthreads();
    }
  }

  if (t < KTOP){
    const float* bp = boxes + ((size_t)b*NBOX + sel[t])*4;
    float x1=bp[0], y1=bp[1], x2=bp[2], y2=bp[3];
    float* o = nmsbuf + ((size_t)b*KTOP + t)*6;
    o[0]=x1; o[1]=y1; o[2]=x2; o[3]=y2;
    o[4]=selsc[t];
    o[5]=fmaxf(x2-x1,0.0f)*fmaxf(y2-y1,0.0f);
  }
}

// ---------------- kernel B: single-wave register NMS + final write ----------------
__global__ __launch_bounds__(64, 1) void nms_kernel(
    const float* __restrict__ nmsbuf, const int* __restrict__ mcnt,
    float* __restrict__ out)
{
  const int b = blockIdx.x;
  const int lane = threadIdx.x;
  int Mtop = mcnt[b]; if (Mtop > KTOP) Mtop = KTOP;
  float X1[5],Y1[5],X2[5],Y2[5],AR[5],SC[5];
  unsigned keepm = 0;
  #pragma unroll
  for (int s5=0; s5<5; ++s5){
    int j = lane + 64*s5;
    if (j < KTOP){
      const float* p = nmsbuf + ((size_t)b*KTOP + j)*6;
      X1[s5]=p[0]; Y1[s5]=p[1]; X2[s5]=p[2]; Y2[s5]=p[3];
      SC[s5]=p[4]; AR[s5]=p[5];
      keepm |= (1u << s5);
    } else { X1[s5]=0;Y1[s5]=0;X2[s5]=0;Y2[s5]=0;AR[s5]=0;SC[s5]=0; }
  }
  for (int i=0;i<Mtop;i++){
    const int iw = i & 63, is = i >> 6;
    unsigned km = __shfl(keepm, iw);
    if ((km >> is) & 1u){
      float sx1 = (is==0)?X1[0]:(is==1)?X1[1]:(is==2)?X1[2]:(is==3)?X1[3]:X1[4];
      float sy1 = (is==0)?Y1[0]:(is==1)?Y1[1]:(is==2)?Y1[2]:(is==3)?Y1[3]:Y1[4];
      float sx2 = (is==0)?X2[0]:(is==1)?X2[1]:(is==2)?X2[2]:(is==3)?X2[3]:X2[4];
      float sy2 = (is==0)?Y2[0]:(is==1)?Y2[1]:(is==2)?Y2[2]:(is==3)?Y2[3]:Y2[4];
      float sa  = (is==0)?AR[0]:(is==1)?AR[1]:(is==2)?AR[2]:(is==3)?AR[3]:AR[4];
      float bx1=__shfl(sx1,iw), by1=__shfl(sy1,iw);
      float bx2=__shfl(sx2,iw), by2=__shfl(sy2,iw);
      float ba =__shfl(sa ,iw);
      #pragma unroll
      for (int s5=0; s5<5; ++s5){
        int j = lane + 64*s5;
        if (((keepm >> s5) & 1u) && j > i){
          float ix1=fmaxf(bx1,X1[s5]);
          float iy1=fmaxf(by1,Y1[s5]);
          float ix2=fminf(bx2,X2[s5]);
          float iy2=fminf(by2,Y2[s5]);
          float inter=fmaxf(ix2-ix1,0.0f)*fmaxf(iy2-iy1,0.0f);
          float iou = inter/(ba+AR[s5]-inter+1e-7f);
          if (iou > 0.5f) keepm &= ~(1u << s5);
        }
      }
    }
  }
  #pragma unroll
  for (int s5=0; s5<5; ++s5){
    int j = lane + 64*s5;
    if (j < KTOP){
      float scv = SC[s5];
      float kf  = (((keepm >> s5) & 1u) && scv > 0.0f) ? 1.0f : 0.0f;
      float* o = out + ((size_t)b*KTOP + j)*6;
      o[0]=X1[s5]; o[1]=Y1[s5]; o[2]=X2[s5]; o[3]=Y2[s5];
      o[4]=scv; o[5]=kf;
    }
  }
}

extern "C" void kernel_launch(void* const* d_in, const int* in_sizes, int n_in,
                              void* d_out, int out_size, void* d_ws, size_t ws_size,
                              hipStream_t stream) {
  const float* x  = (const float*)d_in[0];
  const float* W1 = (const float*)d_in[1];
  const float* b1 = (const float*)d_in[2];
  const float* W2 = (const float*)d_in[3];
  const float* b2 = (const float*)d_in[4];
  const float* W3 = (const float*)d_in[5];
  const float* b3 = (const float*)d_in[6];
  const float* Wh = (const float*)d_in[7];
  const float* bh = (const float*)d_in[8];
  float* out = (float*)d_out;
  float* ws  = (float*)d_ws;

  float* f1     = ws;               // 16x16x320x320 = 26,214,400
  float* f2     = ws + 26214400;    // 16x32x160x160 = 13,107,200
  float* boxes  = ws;               // reuse f1 region: 16x19200x4 (f1 dead after conv2)
  float* scores = boxes + 1228800;  // 16x19200
  float* nmsbuf = scores + 307200;  // 16x300x6
  int*   mcnt   = (int*)(nmsbuf + 28800);

  // conv1: 3->16, tile 64x16, C=8, ICCH=1, MINW=1 -> 1600 blocks (round-0 exact)
  conv3x3s2_v7<3,16,8,1,640,320,64,16,1><<<5*20*BATCH, 256, 0, stream>>>(x,  W1, b1, f1);
  // conv2: v12 = SGPR weights (no wlds), LDS 19KB, MINW=1 (proven round 7)
  conv2_v12<<<5*10*BATCH, 256, 0, stream>>>(f1, W2, b2, f2);
  // conv3 + head + decode fused v5: 128 threads, C=8/py=2 (best LDS-reads-per-FMA)
  conv3_decode_fused<<<5*10*BATCH, 128, 0, stream>>>(f2, W3, b3, Wh, bh, boxes, scores);

  topk_kernel<<<BATCH, 1024, 0, stream>>>(boxes, scores, nmsbuf, mcnt);
  nms_kernel<<<BATCH, 64, 0, stream>>>(nmsbuf, mcnt, out);
}

// Round 12
// 344.855 us; speedup vs baseline: 1.2194x; 1.2194x over previous
//
#include <hip/hip_runtime.h>
#include <math.h>

#define BATCH 16
#define GRID  80
#define NANCH 3
#define KTOP  300
#define NBOX  (NANCH*GRID*GRID)   // 19200
#define SORT_CAP 8192

__device__ __forceinline__ float sigmoidf_(float x){ return 1.0f/(1.0f+expf(-x)); }

// ---------------- conv1 v13: SGPR weights (conv2_v12 pattern transplanted) ----------------
// og = t/128 is wave-uniform; W1 = 16*3*9*4 = 1728 B << scalar cache (the round-10
// failure was W3=73KB; conv2's 18KB and this 1.7KB both fit). Deletes wlds: removes
// 18 of 33 LDS instrs/chunk from an LDS-issue-bound loop and ~72 hoisted weight VGPRs
// -> natural VGPR ~112 <= 128 -> 4 blocks/CU (LDS 35904 B). MINW=1 (allocator law:
// never give a feasible waves hint). FMA order per acc element (ch, ky, kx) ascending
// -> bit-exact vs round-0 v7 conv1. Canary: WRITE ~105 MB (spill would inflate it).
__global__ __launch_bounds__(256, 1) void conv1_v13(
    const float* __restrict__ in, const float* __restrict__ w,
    const float* __restrict__ bias, float* __restrict__ out)
{
  constexpr int CIN=3, COUT=16, HIN=640, HOUT=320, TX=64, TY=16;
  constexpr int NTX=16, NTY=8;
  constexpr int C=8;
  constexpr int HR=2*TY+1;              // 33
  constexpr int NB4=(2*TX+1)/4;         // 32
  constexpr int PADC=((2*TX+1+3)/4)*4+4;// 136 (mod 32 = 8, same swizzle family)
  constexpr int ILDSC=HR*PADC;          // 4488
  constexpr int TBX=HOUT/TX, TBY=HOUT/TY;  // 5, 20
  constexpr int NH4=HR*NB4;             // 1056
  constexpr int NH1=HR;                 // 33
  constexpr int NLD4=(NH4+255)/256;     // 5
  __shared__ float ilds[2][ILDSC];      // 35904 B

  const int t  = threadIdx.x;
  const int sx = t % NTX;
  const int sy = (t / NTX) % NTY;
  const int og = t / 128;                           // wave-uniform (2 waves per og)
  const int ocb = __builtin_amdgcn_readfirstlane(og * C);

  int blk = blockIdx.x;
  const int bx = blk % TBX; blk /= TBX;
  const int by = blk % TBY; blk /= TBY;
  const int b  = blk;

  const int ix0 = bx*2*TX, iy0 = by*2*TY;
  const int ylim = (iy0 + HR <= HIN) ? HR : (HIN - iy0);
  const bool tail_ok = (ix0 + NB4*4 < HIN);

  float4 hreg[NLD4];
  float  treg;

  auto load_regs = [&](int c0){
    #pragma unroll
    for (int l=0;l<NLD4;++l){
      int i = t + 256*l;
      float4 v = make_float4(0.f,0.f,0.f,0.f);
      if (i < NH4){
        int r = i/NB4, m = i - r*NB4;
        if (r < ylim)
          v = *(const float4*)(in + (size_t)(b*CIN + c0)*HIN*HIN
                                  + (size_t)(iy0+r)*HIN + ix0 + 4*m);
      }
      hreg[l] = v;
    }
    {
      float v = 0.f;
      if (t < NH1){
        int r = t;
        if (r < ylim && tail_ok)
          v = in[(size_t)(b*CIN + c0)*HIN*HIN + (size_t)(iy0+r)*HIN + ix0 + NB4*4];
      }
      treg = v;
    }
  };

  auto write_lds = [&](int bufi){
    #pragma unroll
    for (int l=0;l<NLD4;++l){
      int i = t + 256*l;
      if (i < NH4){
        int r = i/NB4, m = i - r*NB4;
        *(float4*)(&ilds[bufi][r*PADC + 4*((r>>2)&1) + 4*m]) = hreg[l];
      }
    }
    if (t < NH1){
      int r = t;
      ilds[bufi][r*PADC + 4*((r>>2)&1) + NB4*4] = treg;
    }
  };

  float acc[C][2][4];
  #pragma unroll
  for (int j=0;j<C;++j){
    float bv = bias[ocb+j];
    #pragma unroll
    for (int py=0;py<2;++py)
      #pragma unroll
      for (int px=0;px<4;++px) acc[j][py][px]=bv;
  }

  load_regs(0);
  write_lds(0);
  __syncthreads();

  #pragma unroll 1
  for (int ch=0; ch<CIN; ++ch){
    const int cur = ch & 1;
    if (ch+1 < CIN) load_regs(ch+1);

    // wave-uniform weight base: w[(ocb+j)*CIN + ch][ky][kx]
    const float* wg = w + ((size_t)ocb*CIN + ch)*9;
    const float* ipb = &ilds[cur][0] + 8*sx;

    #pragma unroll
    for (int ky=0;ky<3;++ky){
      float wv[3][8];
      #pragma unroll
      for (int j=0;j<8;++j){
        #pragma unroll
        for (int kx=0;kx<3;++kx)
          wv[kx][j] = wg[(size_t)j*(CIN*9) + ky*3 + kx];
      }
      // ---- py=0 half: row 4sy+ky
      {
        float ra[12];
        const int rr0 = 4*sy + ky;
        const float* rp0 = ipb + rr0*PADC + 4*((rr0>>2)&1);
        #pragma unroll
        for (int m=0;m<3;++m){
          float4 v0 = *(const float4*)(rp0 + 4*m);
          ra[4*m+0]=v0.x; ra[4*m+1]=v0.y; ra[4*m+2]=v0.z; ra[4*m+3]=v0.w;
        }
        #pragma unroll
        for (int kx=0;kx<3;++kx){
          #pragma unroll
          for (int px=0;px<4;++px){
            const float xv = ra[2*px+kx];
            acc[0][0][px] += xv*wv[kx][0]; acc[1][0][px] += xv*wv[kx][1];
            acc[2][0][px] += xv*wv[kx][2]; acc[3][0][px] += xv*wv[kx][3];
            acc[4][0][px] += xv*wv[kx][4]; acc[5][0][px] += xv*wv[kx][5];
            acc[6][0][px] += xv*wv[kx][6]; acc[7][0][px] += xv*wv[kx][7];
          }
        }
      }
      // ---- py=1 half: row 4sy+ky+2
      {
        float rb[12];
        const int rr1 = 4*sy + ky + 2;
        const float* rp1 = ipb + rr1*PADC + 4*((rr1>>2)&1);
        #pragma unroll
        for (int m=0;m<3;++m){
          float4 v1 = *(const float4*)(rp1 + 4*m);
          rb[4*m+0]=v1.x; rb[4*m+1]=v1.y; rb[4*m+2]=v1.z; rb[4*m+3]=v1.w;
        }
        #pragma unroll
        for (int kx=0;kx<3;++kx){
          #pragma unroll
          for (int px=0;px<4;++px){
            const float xv = rb[2*px+kx];
            acc[0][1][px] += xv*wv[kx][0]; acc[1][1][px] += xv*wv[kx][1];
            acc[2][1][px] += xv*wv[kx][2]; acc[3][1][px] += xv*wv[kx][3];
            acc[4][1][px] += xv*wv[kx][4]; acc[5][1][px] += xv*wv[kx][5];
            acc[6][1][px] += xv*wv[kx][6]; acc[7][1][px] += xv*wv[kx][7];
          }
        }
      }
    }

    if (ch+1 < CIN) write_lds((ch+1)&1);
    __syncthreads();
  }

  const int oxb = bx*TX + sx*4;
  #pragma unroll
  for (int j=0;j<C;++j){
    int oc = ocb+j;
    #pragma unroll
    for (int py=0;py<2;++py){
      int oy = by*TY + sy*2 + py;
      float4 o4;
      float z0=acc[j][py][0], z1=acc[j][py][1], z2=acc[j][py][2], z3=acc[j][py][3];
      o4.x = z0/(1.0f+expf(-z0));
      o4.y = z1/(1.0f+expf(-z1));
      o4.z = z2/(1.0f+expf(-z2));
      o4.w = z3/(1.0f+expf(-z3));
      *(float4*)(out + ((size_t)(b*COUT+oc)*HOUT + oy)*HOUT + oxb) = o4;
    }
  }
}

// ---------------- conv2 v12: weights via wave-uniform scalar loads (SGPR), no wlds ----------
// (proven round 7; W2=18KB fits scalar L1 -> s_loads are cache hits.)
__global__ __launch_bounds__(256, 1) void conv2_v12(
    const float* __restrict__ in, const float* __restrict__ w,
    const float* __restrict__ bias, float* __restrict__ out)
{
  constexpr int CIN=16, COUT=32, HIN=320, HOUT=160, TX=32, TY=16;
  constexpr int NTX=8, NTY=8;
  constexpr int C=8;
  constexpr int HR=2*TY+1;              // 33
  constexpr int NB4=(2*TX+1)/4;         // 16
  constexpr int PADC=72;
  constexpr int ILDSC=HR*PADC;          // 2376
  constexpr int TBX=HOUT/TX, TBY=HOUT/TY;  // 5, 10
  constexpr int NH4=HR*NB4;             // 528
  constexpr int NH1=HR;                 // 33
  constexpr int NLD4=(NH4+255)/256;     // 3
  __shared__ float ilds[2][ILDSC];      // 19008 B total

  const int t  = threadIdx.x;
  const int sx = t % NTX;
  const int sy = (t / NTX) % NTY;
  const int og = t / 64;                            // == wave id -> wave-uniform
  const int ocb = __builtin_amdgcn_readfirstlane(og * C);  // scalar oc base

  int blk = blockIdx.x;
  const int bx = blk % TBX; blk /= TBX;
  const int by = blk % TBY; blk /= TBY;
  const int b  = blk;

  const int ix0 = bx*2*TX, iy0 = by*2*TY;
  const int ylim = (iy0 + HR <= HIN) ? HR : (HIN - iy0);
  const bool tail_ok = (ix0 + NB4*4 < HIN);

  float4 hreg[NLD4];
  float  treg;

  auto load_regs = [&](int c0){
    #pragma unroll
    for (int l=0;l<NLD4;++l){
      int i = t + 256*l;
      float4 v = make_float4(0.f,0.f,0.f,0.f);
      if (i < NH4){
        int r = i/NB4, m = i - r*NB4;
        if (r < ylim)
          v = *(const float4*)(in + (size_t)(b*CIN + c0)*HIN*HIN
                                  + (size_t)(iy0+r)*HIN + ix0 + 4*m);
      }
      hreg[l] = v;
    }
    {
      float v = 0.f;
      if (t < NH1){
        int r = t;
        if (r < ylim && tail_ok)
          v = in[(size_t)(b*CIN + c0)*HIN*HIN + (size_t)(iy0+r)*HIN + ix0 + NB4*4];
      }
      treg = v;
    }
  };

  auto write_lds = [&](int bufi){
    #pragma unroll
    for (int l=0;l<NLD4;++l){
      int i = t + 256*l;
      if (i < NH4){
        int r = i/NB4, m = i - r*NB4;
        *(float4*)(&ilds[bufi][r*PADC + 4*((r>>2)&1) + 4*m]) = hreg[l];
      }
    }
    if (t < NH1){
      int r = t;
      ilds[bufi][r*PADC + 4*((r>>2)&1) + NB4*4] = treg;
    }
  };

  float acc[C][2][4];
  #pragma unroll
  for (int j=0;j<C;++j){
    float bv = bias[og*C+j];
    #pragma unroll
    for (int py=0;py<2;++py)
      #pragma unroll
      for (int px=0;px<4;++px) acc[j][py][px]=bv;
  }

  load_regs(0);
  write_lds(0);
  __syncthreads();

  #pragma unroll 1
  for (int ch=0; ch<CIN; ++ch){
    const int cur = ch & 1;
    if (ch+1 < CIN) load_regs(ch+1);

    // wave-uniform weight base for this input channel: w[(ocb+j)*CIN + ch][ky][kx]
    const float* wg = w + ((size_t)ocb*CIN + ch)*9;
    const float* ipb = &ilds[cur][0] + 8*sx;

    #pragma unroll
    for (int ky=0;ky<3;++ky){
      // 24 wave-uniform weight scalars for this (ch, ky) -> SGPRs via s_load
      float wv[3][8];
      #pragma unroll
      for (int j=0;j<8;++j){
        #pragma unroll
        for (int kx=0;kx<3;++kx)
          wv[kx][j] = wg[(size_t)j*(CIN*9) + ky*3 + kx];
      }
      // ---- py=0 half: row 4sy+ky (12 live row regs)
      {
        float ra[12];
        const int rr0 = 4*sy + ky;
        const float* rp0 = ipb + rr0*PADC + 4*((rr0>>2)&1);
        #pragma unroll
        for (int m=0;m<3;++m){
          float4 v0 = *(const float4*)(rp0 + 4*m);
          ra[4*m+0]=v0.x; ra[4*m+1]=v0.y; ra[4*m+2]=v0.z; ra[4*m+3]=v0.w;
        }
        #pragma unroll
        for (int kx=0;kx<3;++kx){
          #pragma unroll
          for (int px=0;px<4;++px){
            const float xv = ra[2*px+kx];
            acc[0][0][px] += xv*wv[kx][0]; acc[1][0][px] += xv*wv[kx][1];
            acc[2][0][px] += xv*wv[kx][2]; acc[3][0][px] += xv*wv[kx][3];
            acc[4][0][px] += xv*wv[kx][4]; acc[5][0][px] += xv*wv[kx][5];
            acc[6][0][px] += xv*wv[kx][6]; acc[7][0][px] += xv*wv[kx][7];
          }
        }
      }
      // ---- py=1 half: row 4sy+ky+2
      {
        float rb[12];
        const int rr1 = 4*sy + ky + 2;
        const float* rp1 = ipb + rr1*PADC + 4*((rr1>>2)&1);
        #pragma unroll
        for (int m=0;m<3;++m){
          float4 v1 = *(const float4*)(rp1 + 4*m);
          rb[4*m+0]=v1.x; rb[4*m+1]=v1.y; rb[4*m+2]=v1.z; rb[4*m+3]=v1.w;
        }
        #pragma unroll
        for (int kx=0;kx<3;++kx){
          #pragma unroll
          for (int px=0;px<4;++px){
            const float xv = rb[2*px+kx];
            acc[0][1][px] += xv*wv[kx][0]; acc[1][1][px] += xv*wv[kx][1];
            acc[2][1][px] += xv*wv[kx][2]; acc[3][1][px] += xv*wv[kx][3];
            acc[4][1][px] += xv*wv[kx][4]; acc[5][1][px] += xv*wv[kx][5];
            acc[6][1][px] += xv*wv[kx][6]; acc[7][1][px] += xv*wv[kx][7];
          }
        }
      }
    }

    if (ch+1 < CIN) write_lds((ch+1)&1);
    __syncthreads();
  }

  const int oxb = bx*TX + sx*4;
  #pragma unroll
  for (int j=0;j<C;++j){
    int oc = og*C+j;
    #pragma unroll
    for (int py=0;py<2;++py){
      int oy = by*TY + sy*2 + py;
      float4 o4;
      float z0=acc[j][py][0], z1=acc[j][py][1], z2=acc[j][py][2], z3=acc[j][py][3];
      o4.x = z0/(1.0f+expf(-z0));
      o4.y = z1/(1.0f+expf(-z1));
      o4.z = z2/(1.0f+expf(-z2));
      o4.w = z3/(1.0f+expf(-z3));
      *(float4*)(out + ((size_t)(b*COUT+oc)*HOUT + oy)*HOUT + oxb) = o4;
    }
  }
}

// ---------------- conv3 + head + decode, fused v3 (round-9 best: 99.5us) ----------------
// Fused ledger: v2=100, v3=99.5 (best), v4=119 (s_load thrash), v5=155 (lost waves).
// v3 structure is the local ceiling (~69us LDS-pipe floor + barriers); reverted here.
__global__ __launch_bounds__(256, 1) void conv3_decode_fused(
    const float* __restrict__ in,   // f2
    const float* __restrict__ w,    // W3
    const float* __restrict__ bias, // b3
    const float* __restrict__ wh,   // Wh [48][64]
    const float* __restrict__ bh,   // bh [48]
    float* __restrict__ boxes, float* __restrict__ scores)
{
  constexpr int CIN=32, COUT=64, C=8, ICCH=4, HIN=160, TX=16, TY=8;
  constexpr int HR=2*TY+1, HC=2*TX+1;                 // 17,33
  constexpr int NB4=HC/4;                             // 8
  constexpr int PADC=((HC+3)/4)*4+4;                  // 40
  constexpr int ILDSC=HR*PADC;                        // 680
  constexpr int TBX=5, TBY=10;
  constexpr int NCH=CIN/ICCH;                         // 8
  constexpr int NH4=ICCH*HR*NB4;                      // 544
  constexpr int NH1=ICCH*HR;                          // 68
  constexpr int NWT=ICCH*9*COUT;                      // 2304
  constexpr int NLD4=(NH4+255)/256, NLD1=(NH1+255)/256, NLDW=(NWT+255)/256;
  constexpr int F3S=69;                               // f3l row stride (mod 32 = 5)
  __shared__ float smem[10048];
  float* ildsb = smem;              // [2][ICCH*ILDSC] = 5440
  float* wldsb = smem + 5440;       // [2][NWT] = 4608 (ends 10048)
  float* f3l   = smem;              // [128][69] = 8832 aliased (post-conv)

  const int t  = threadIdx.x;
  const int sp = t & 31;
  const int sx = sp & 3;            // 4 px each
  const int sy = sp >> 2;           // 1 output row each (0..7)
  const int og = t >> 5;            // 8 oc-groups of 8
  int blk = blockIdx.x;
  const int bx = blk % TBX; blk /= TBX;
  const int by = blk % TBY; blk /= TBY;
  const int b  = blk;

  const int ix0 = bx*2*TX, iy0 = by*2*TY;
  const int ylim = (iy0 + HR <= HIN) ? HR : (HIN - iy0);
  const bool tail_ok = (ix0 + NB4*4 < HIN);

  float4 hreg[NLD4];
  float  treg[NLD1];
  float  wreg[NLDW];

  auto load_regs = [&](int c0){
    #pragma unroll
    for (int l=0;l<NLD4;++l){
      int i = t + 256*l;
      float4 v = make_float4(0.f,0.f,0.f,0.f);
      if (i < NH4){
        int c = i/(HR*NB4), rm = i - c*(HR*NB4);
        int r = rm/NB4, m = rm - r*NB4;
        if (r < ylim)
          v = *(const float4*)(in + (size_t)(b*CIN + c0 + c)*HIN*HIN
                                  + (size_t)(iy0+r)*HIN + ix0 + 4*m);
      }
      hreg[l] = v;
    }
    #pragma unroll
    for (int l=0;l<NLD1;++l){
      int i = t + 256*l;
      float v = 0.f;
      if (i < NH1){
        int c = i/HR, r = i - c*HR;
        if (r < ylim && tail_ok)
          v = in[(size_t)(b*CIN + c0 + c)*HIN*HIN + (size_t)(iy0+r)*HIN + ix0 + NB4*4];
      }
      treg[l] = v;
    }
    #pragma unroll
    for (int l=0;l<NLDW;++l){
      int i = t + 256*l;
      float v = 0.f;
      if (i < NWT){
        int oc  = i % COUT;
        int k   = (i / COUT) % 9;
        int icl = i / (9*COUT);
        v = w[((size_t)oc*CIN + c0+icl)*9 + k];
      }
      wreg[l] = v;
    }
  };

  auto write_lds = [&](int bufi){
    #pragma unroll
    for (int l=0;l<NLD4;++l){
      int i = t + 256*l;
      if (i < NH4){
        int c = i/(HR*NB4), rm = i - c*(HR*NB4);
        int r = rm/NB4, m = rm - r*NB4;
        *(float4*)(&ildsb[bufi*(ICCH*ILDSC) + c*ILDSC + r*PADC + 4*((r>>2)&1) + 4*m]) = hreg[l];
      }
    }
    #pragma unroll
    for (int l=0;l<NLD1;++l){
      int i = t + 256*l;
      if (i < NH1){
        int c = i/HR, r = i - c*HR;
        ildsb[bufi*(ICCH*ILDSC) + c*ILDSC + r*PADC + 4*((r>>2)&1) + NB4*4] = treg[l];
      }
    }
    #pragma unroll
    for (int l=0;l<NLDW;++l){
      int i = t + 256*l;
      if (i < NWT) wldsb[bufi*NWT + i] = wreg[l];
    }
  };

  float acc[C][4];
  #pragma unroll
  for (int j=0;j<C;++j){
    float bv = bias[og*C+j];
    #pragma unroll
    for (int px=0;px<4;++px) acc[j][px]=bv;
  }

  load_regs(0);
  write_lds(0);
  __syncthreads();

  #pragma unroll 1
  for (int ch=0; ch<NCH; ++ch){
    const int cur = ch & 1;
    if (ch+1 < NCH) load_regs((ch+1)*ICCH);

    #pragma unroll 1
    for (int icl=0; icl<ICCH; ++icl){
      const float* wpb = &wldsb[cur*NWT + icl*9*COUT] + og*C;
      const float* ipb = &ildsb[cur*(ICCH*ILDSC) + icl*ILDSC] + 8*sx;
      #pragma unroll
      for (int ky=0;ky<3;++ky){
        float row[12];
        {
          const int rr = 2*sy + ky;
          const float* rp = ipb + rr*PADC + 4*((rr>>2)&1);
          #pragma unroll
          for (int m=0;m<3;++m){
            float4 v4 = *(const float4*)(rp + 4*m);
            row[4*m+0]=v4.x; row[4*m+1]=v4.y; row[4*m+2]=v4.z; row[4*m+3]=v4.w;
          }
        }
        #pragma unroll
        for (int kx=0;kx<3;++kx){
          const float4 wa = *(const float4*)(wpb + (ky*3+kx)*COUT);
          const float4 wb = *(const float4*)(wpb + (ky*3+kx)*COUT + 4);
          #pragma unroll
          for (int px=0;px<4;++px){
            const float xv = row[2*px+kx];
            acc[0][px] += xv*wa.x; acc[1][px] += xv*wa.y;
            acc[2][px] += xv*wa.z; acc[3][px] += xv*wa.w;
            acc[4][px] += xv*wb.x; acc[5][px] += xv*wb.y;
            acc[6][px] += xv*wb.z; acc[7][px] += xv*wb.w;
          }
        }
      }
    }

    if (ch+1 < NCH) write_lds((ch+1)&1);
    __syncthreads();
  }

  // ---- epilogue: SiLU -> LDS f3 tile (stride 69, conflict-light)
  #pragma unroll
  for (int j=0;j<C;++j){
    int oc = og*C+j;
    #pragma unroll
    for (int px=0;px<4;++px){
      int pxidx = sy*16 + sx*4+px;
      float z = acc[j][px];
      f3l[pxidx*F3S + oc] = z/(1.0f+expf(-z));
    }
  }
  __syncthreads();

  // ---- head (6 channels) + sigmoid + decode + write; Wh/bh direct from global
  const float awv[3] = {4.0f, 8.0f, 13.0f};
  const float ahv[3] = {5.0f, 10.0f, 16.0f};
  const int chs[6] = {0,1,2,3,4,15};
  for (int q=t; q<384; q+=256){
    int p = q & 127;
    const int ua = __builtin_amdgcn_readfirstlane(q >> 7);
    float ac[6];
    #pragma unroll
    for (int j=0;j<6;++j) ac[j] = bh[ua*16 + chs[j]];
    const float* fp = f3l + p*F3S;
    const float* wp = wh + (size_t)ua*16*64;
    #pragma unroll 4
    for (int ic=0; ic<64; ic+=4){
      float4 fv = *(const float4*)(fp + ic);
      #pragma unroll
      for (int j=0;j<6;++j){
        float4 wv = *(const float4*)(wp + chs[j]*64 + ic);
        ac[j] += fv.x*wv.x; ac[j] += fv.y*wv.y;
        ac[j] += fv.z*wv.z; ac[j] += fv.w*wv.w;
      }
    }
    float p0 = sigmoidf_(ac[0]);
    float p1 = sigmoidf_(ac[1]);
    float p2 = sigmoidf_(ac[2]);
    float p3 = sigmoidf_(ac[3]);
    float p4 = sigmoidf_(ac[4]);
    float p15= sigmoidf_(ac[5]);
    int gx = bx*16 + (p & 15), gy = by*8 + (p >> 4);
    float cx = (p0*2.0f - 0.5f + (float)gx)*8.0f;
    float cy = (p1*2.0f - 0.5f + (float)gy)*8.0f;
    float ww = p2*2.0f; ww = ww*ww*awv[ua];
    float hh = p3*2.0f; hh = hh*hh*ahv[ua];
    float sc = p4*p15;
    sc = (sc > 0.5f) ? sc : 0.0f;
    int bi = ua*GRID*GRID + gy*GRID + gx;
    float* bo = boxes + ((size_t)b*NBOX + bi)*4;
    bo[0] = cx - ww*0.5f;
    bo[1] = cy - hh*0.5f;
    bo[2] = cx + ww*0.5f;
    bo[3] = cy + hh*0.5f;
    scores[(size_t)b*NBOX + bi] = sc;
  }
}

// ---------------- kernel A: compact + bitonic-sort top-K + gather ----------------
__global__ __launch_bounds__(1024) void topk_kernel(
    const float* __restrict__ boxes, const float* __restrict__ scores,
    float* __restrict__ nmsbuf, int* __restrict__ mcnt)
{
  __shared__ unsigned long long keys[SORT_CAP];  // 64 KB
  __shared__ int   cntM;
  __shared__ int   sel[KTOP];
  __shared__ float selsc[KTOP];
  __shared__ int   wsum[16];
  __shared__ float rs[16];
  __shared__ int   ri[16];
  __shared__ unsigned clm[(NBOX+31)/32];

  const int b = blockIdx.x;
  const int t = threadIdx.x;
  const int lane = t & 63, wv = t >> 6;
  const float* scp = scores + (size_t)b*NBOX;

  if (t == 0) cntM = 0;
  __syncthreads();

  for (int i=t; i<NBOX; i+=1024){
    float v = scp[i];
    if (v > 0.0f){
      int p = atomicAdd(&cntM, 1);
      if (p < SORT_CAP)
        keys[p] = ((unsigned long long)__float_as_uint(v) << 32)
                | (unsigned)(0xFFFFFFFFu - (unsigned)i);
    }
  }
  __syncthreads();
  const int M = cntM;
  if (t == 0) mcnt[b] = M;

  if (M <= SORT_CAP){
    int P = 64; while (P < M) P <<= 1;
    for (int i=t; i<P; i+=1024) if (i >= M) keys[i] = 0ULL;
    __syncthreads();
    for (int k=2; k<=P; k<<=1){
      for (int j=k>>1; j>0; j>>=1){
        for (int i=t; i<P; i+=1024){
          int ixj = i ^ j;
          if (ixj > i){
            unsigned long long a = keys[i], c = keys[ixj];
            bool up = ((i & k) == 0);
            if (up ? (a < c) : (a > c)){ keys[i] = c; keys[ixj] = a; }
          }
        }
        __syncthreads();
      }
    }
    const int top = (M < KTOP) ? M : KTOP;
    if (t < top){
      unsigned long long kk = keys[t];
      selsc[t] = __uint_as_float((unsigned)(kk >> 32));
      sel[t]   = (int)(0xFFFFFFFFu - (unsigned)(kk & 0xFFFFFFFFu));
    }
    if (M < KTOP){
      const int need = KTOP - M;
      const int Cc = (NBOX + 1023)/1024;
      int lo = t*Cc, hi = lo+Cc; if (hi > NBOX) hi = NBOX; if (lo > NBOX) lo = NBOX;
      int zc = 0;
      for (int i=lo;i<hi;i++) if (scp[i] <= 0.0f) zc++;
      int v = zc;
      #pragma unroll
      for (int off=1; off<64; off<<=1){
        int n = __shfl_up(v, off);
        if (lane >= off) v += n;
      }
      if (lane == 63) wsum[wv] = v;
      __syncthreads();
      if (t == 0){
        int a = 0;
        for (int w=0; w<16; w++){ int tmp = wsum[w]; wsum[w] = a; a += tmp; }
      }
      __syncthreads();
      int r = wsum[wv] + v - zc;
      for (int i=lo;i<hi;i++){
        if (scp[i] <= 0.0f){
          if (r < need){ sel[M+r] = i; selsc[M+r] = 0.0f; }
          r++;
        }
      }
    }
    __syncthreads();
  } else {
    for (int i=t; i<(NBOX+31)/32; i+=1024) clm[i] = 0u;
    __syncthreads();
    for (int k=0;k<KTOP;k++){
      float best = -2.0f; int bi = NBOX;
      for (int i=t;i<NBOX;i+=1024){
        if (!((clm[i>>5] >> (i&31)) & 1u)){
          float v = scp[i];
          if (v > best){ best=v; bi=i; }
        }
      }
      #pragma unroll
      for (int off=32; off>0; off>>=1){
        float ov = __shfl_down(best, off);
        int   oi = __shfl_down(bi,   off);
        if (ov > best || (ov == best && oi < bi)){ best=ov; bi=oi; }
      }
      if (lane == 0){ rs[wv]=best; ri[wv]=bi; }
      __syncthreads();
      if (t == 0){
        for (int w=1; w<16; w++)
          if (rs[w] > best || (rs[w] == best && ri[w] < bi)){ best=rs[w]; bi=ri[w]; }
        sel[k]=bi; selsc[k]=best; clm[bi>>5] |= (1u << (bi&31));
      }
      __syncthreads();
    }
  }

  if (t < KTOP){
    const float* bp = boxes + ((size_t)b*NBOX + sel[t])*4;
    float x1=bp[0], y1=bp[1], x2=bp[2], y2=bp[3];
    float* o = nmsbuf + ((size_t)b*KTOP + t)*6;
    o[0]=x1; o[1]=y1; o[2]=x2; o[3]=y2;
    o[4]=selsc[t];
    o[5]=fmaxf(x2-x1,0.0f)*fmaxf(y2-y1,0.0f);
  }
}

// ---------------- kernel B: single-wave register NMS + final write ----------------
__global__ __launch_bounds__(64, 1) void nms_kernel(
    const float* __restrict__ nmsbuf, const int* __restrict__ mcnt,
    float* __restrict__ out)
{
  const int b = blockIdx.x;
  const int lane = threadIdx.x;
  int Mtop = mcnt[b]; if (Mtop > KTOP) Mtop = KTOP;
  float X1[5],Y1[5],X2[5],Y2[5],AR[5],SC[5];
  unsigned keepm = 0;
  #pragma unroll
  for (int s5=0; s5<5; ++s5){
    int j = lane + 64*s5;
    if (j < KTOP){
      const float* p = nmsbuf + ((size_t)b*KTOP + j)*6;
      X1[s5]=p[0]; Y1[s5]=p[1]; X2[s5]=p[2]; Y2[s5]=p[3];
      SC[s5]=p[4]; AR[s5]=p[5];
      keepm |= (1u << s5);
    } else { X1[s5]=0;Y1[s5]=0;X2[s5]=0;Y2[s5]=0;AR[s5]=0;SC[s5]=0; }
  }
  for (int i=0;i<Mtop;i++){
    const int iw = i & 63, is = i >> 6;
    unsigned km = __shfl(keepm, iw);
    if ((km >> is) & 1u){
      float sx1 = (is==0)?X1[0]:(is==1)?X1[1]:(is==2)?X1[2]:(is==3)?X1[3]:X1[4];
      float sy1 = (is==0)?Y1[0]:(is==1)?Y1[1]:(is==2)?Y1[2]:(is==3)?Y1[3]:Y1[4];
      float sx2 = (is==0)?X2[0]:(is==1)?X2[1]:(is==2)?X2[2]:(is==3)?X2[3]:X2[4];
      float sy2 = (is==0)?Y2[0]:(is==1)?Y2[1]:(is==2)?Y2[2]:(is==3)?Y2[3]:Y2[4];
      float sa  = (is==0)?AR[0]:(is==1)?AR[1]:(is==2)?AR[2]:(is==3)?AR[3]:AR[4];
      float bx1=__shfl(sx1,iw), by1=__shfl(sy1,iw);
      float bx2=__shfl(sx2,iw), by2=__shfl(sy2,iw);
      float ba =__shfl(sa ,iw);
      #pragma unroll
      for (int s5=0; s5<5; ++s5){
        int j = lane + 64*s5;
        if (((keepm >> s5) & 1u) && j > i){
          float ix1=fmaxf(bx1,X1[s5]);
          float iy1=fmaxf(by1,Y1[s5]);
          float ix2=fminf(bx2,X2[s5]);
          float iy2=fminf(by2,Y2[s5]);
          float inter=fmaxf(ix2-ix1,0.0f)*fmaxf(iy2-iy1,0.0f);
          float iou = inter/(ba+AR[s5]-inter+1e-7f);
          if (iou > 0.5f) keepm &= ~(1u << s5);
        }
      }
    }
  }
  #pragma unroll
  for (int s5=0; s5<5; ++s5){
    int j = lane + 64*s5;
    if (j < KTOP){
      float scv = SC[s5];
      float kf  = (((keepm >> s5) & 1u) && scv > 0.0f) ? 1.0f : 0.0f;
      float* o = out + ((size_t)b*KTOP + j)*6;
      o[0]=X1[s5]; o[1]=Y1[s5]; o[2]=X2[s5]; o[3]=Y2[s5];
      o[4]=scv; o[5]=kf;
    }
  }
}

extern "C" void kernel_launch(void* const* d_in, const int* in_sizes, int n_in,
                              void* d_out, int out_size, void* d_ws, size_t ws_size,
                              hipStream_t stream) {
  const float* x  = (const float*)d_in[0];
  const float* W1 = (const float*)d_in[1];
  const float* b1 = (const float*)d_in[2];
  const float* W2 = (const float*)d_in[3];
  const float* b2 = (const float*)d_in[4];
  const float* W3 = (const float*)d_in[5];
  const float* b3 = (const float*)d_in[6];
  const float* Wh = (const float*)d_in[7];
  const float* bh = (const float*)d_in[8];
  float* out = (float*)d_out;
  float* ws  = (float*)d_ws;

  float* f1     = ws;               // 16x16x320x320 = 26,214,400
  float* f2     = ws + 26214400;    // 16x32x160x160 = 13,107,200
  float* boxes  = ws;               // reuse f1 region: 16x19200x4 (f1 dead after conv2)
  float* scores = boxes + 1228800;  // 16x19200
  float* nmsbuf = scores + 307200;  // 16x300x6
  int*   mcnt   = (int*)(nmsbuf + 28800);

  // conv1: v13 = SGPR weights (W1=1.7KB), LDS 35.9KB, MINW=1 -> target 4 blk/CU
  conv1_v13<<<5*20*BATCH, 256, 0, stream>>>(x,  W1, b1, f1);
  // conv2: v12 = SGPR weights (no wlds), LDS 19KB, MINW=1 (proven round 7)
  conv2_v12<<<5*10*BATCH, 256, 0, stream>>>(f1, W2, b2, f2);
  // conv3 + head + decode fused v3 (round-9 best, 99.5us)
  conv3_decode_fused<<<5*10*BATCH, 256, 0, stream>>>(f2, W3, b3, Wh, bh, boxes, scores);

  topk_kernel<<<BATCH, 1024, 0, stream>>>(boxes, scores, nmsbuf, mcnt);
  nms_kernel<<<BATCH, 64, 0, stream>>>(nmsbuf, mcnt, out);
}